// Round 3
// baseline (266.586 us; speedup 1.0000x reference)
//
#include <hip/hip_runtime.h>
#include <hip/hip_bf16.h>
#include <math.h>

#define L 2048
#define NB 16
#define ROWS_PER_BLOCK 16
#define THREADS 256
#define GAF_EPS 1e-8f

typedef float f32x4 __attribute__((ext_vector_type(4)));  // native vec: nontemporal-store OK

// gaf[b,i,j] = cos(phi_i + phi_j) = c_i*c_j - s_i*s_j
// with c = clip(2*(x-min)/(max-min+eps) - 1, -1+eps, 1-eps), s = sqrt(1-c^2).
//
// R1 post-mortem: fused version ran at 600 cyc/store-iteration (latency-
// serialized: LDS reads + stores sharing waitcnt in the inner loop).
// Fix: split prep/stream; stream kernel's store loop has ZERO memory reads —
// all operands in registers before the loop.

// ---- Kernel 1: per-batch min/max + c/s table into workspace ----
// ws layout: per batch b: c[L] at ws + b*2L, s[L] at ws + b*2L + L.
__global__ __launch_bounds__(THREADS) void gaf_prep(const float* __restrict__ x,
                                                    float* __restrict__ ws) {
    __shared__ float red[8];
    const int b = blockIdx.x;
    const int t = threadIdx.x;
    const float* __restrict__ xrow = x + (size_t)b * L;

    float v[8];
    float mn = INFINITY, mx = -INFINITY;
#pragma unroll
    for (int k = 0; k < 8; ++k) {
        v[k] = xrow[t + k * THREADS];
        mn = fminf(mn, v[k]);
        mx = fmaxf(mx, v[k]);
    }
#pragma unroll
    for (int off = 32; off > 0; off >>= 1) {
        mn = fminf(mn, __shfl_down(mn, off));
        mx = fmaxf(mx, __shfl_down(mx, off));
    }
    const int wave = t >> 6;
    if ((t & 63) == 0) { red[wave] = mn; red[4 + wave] = mx; }
    __syncthreads();
    if (t == 0) {
        red[0] = fminf(fminf(red[0], red[1]), fminf(red[2], red[3]));
        red[4] = fmaxf(fmaxf(red[4], red[5]), fmaxf(red[6], red[7]));
    }
    __syncthreads();
    mn = red[0];
    mx = red[4];
    const float inv = 1.0f / (mx - mn + GAF_EPS);

    float* __restrict__ cb = ws + (size_t)b * 2 * L;
    float* __restrict__ sb = cb + L;
#pragma unroll
    for (int k = 0; k < 8; ++k) {
        float c = 2.0f * ((v[k] - mn) * inv) - 1.0f;
        c = fminf(fmaxf(c, -1.0f + GAF_EPS), 1.0f - GAF_EPS);
        const int idx = t + k * THREADS;
        cb[idx] = c;
        sb[idx] = sqrtf(fmaxf(1.0f - c * c, 0.0f));
    }
}

// ---- Kernel 2: pure outer-product streamer ----
// Block -> (batch b, 16 rows starting at i0). Thread t owns 8 columns
// (float4 at j4=t and j4=t+256). All operands register-resident before the
// store loop: 16 row scalars + 4 float4 col vectors.
__global__ __launch_bounds__(THREADS) void gaf_stream(const float* __restrict__ ws,
                                                      float* __restrict__ out) {
    const int b = blockIdx.x >> 7;            // /128
    const int i0 = (blockIdx.x & 127) << 4;   // *16
    const int t = threadIdx.x;

    const float* __restrict__ cb = ws + (size_t)b * 2 * L;
    const float* __restrict__ sb = cb + L;

    // column operands (coalesced, L2-hit)
    const f32x4 cj0 = ((const f32x4*)cb)[t];
    const f32x4 cj1 = ((const f32x4*)cb)[t + THREADS];
    const f32x4 sj0 = ((const f32x4*)sb)[t];
    const f32x4 sj1 = ((const f32x4*)sb)[t + THREADS];

    // row operands (wave-uniform address -> scalar loads, hoisted)
    float ci[ROWS_PER_BLOCK], si[ROWS_PER_BLOCK];
#pragma unroll
    for (int i = 0; i < ROWS_PER_BLOCK; ++i) {
        ci[i] = cb[i0 + i];
        si[i] = sb[i0 + i];
    }

    float* __restrict__ ob = out + ((size_t)b * L + (size_t)i0) * L;
#pragma unroll
    for (int i = 0; i < ROWS_PER_BLOCK; ++i) {
        const float c = ci[i], s = si[i];
        const f32x4 o0 = c * cj0 - s * sj0;
        const f32x4 o1 = c * cj1 - s * sj1;
        f32x4* __restrict__ orow = (f32x4*)(ob + (size_t)i * L);
        __builtin_nontemporal_store(o0, orow + t);
        __builtin_nontemporal_store(o1, orow + t + THREADS);
    }
}

extern "C" void kernel_launch(void* const* d_in, const int* in_sizes, int n_in,
                              void* d_out, int out_size, void* d_ws, size_t ws_size,
                              hipStream_t stream) {
    const float* x = (const float*)d_in[0];
    float* out = (float*)d_out;
    float* ws = (float*)d_ws;   // needs 16*2*2048*4 = 256 KiB
    gaf_prep<<<dim3(NB), THREADS, 0, stream>>>(x, ws);
    gaf_stream<<<dim3(NB * (L / ROWS_PER_BLOCK)), THREADS, 0, stream>>>(ws, out);
}